// Round 8
// baseline (285.356 us; speedup 1.0000x reference)
//
#include <hip/hip_runtime.h>
#include <stdint.h>

// Problem: BahdanauAttention  H=512, L=2, B=64, T=2048
// scores[t,b] = Wo . tanh( enc[t,b,:] @ We^T + comb[b,:] )   (bo dropped: softmax-invariant)
// comb[b,:]   = mean_l(hidden[l,b,:]) @ Wh^T + bh + be
// out[b,t]    = masked softmax over t < enc_len[b]
//
// R8 = R5-streaming fixed. Block = 256 rows x 128-col panel, 512 thr (8 waves,
// 32 rows each). B panel 128 KB -> LDS via glds ONCE (one barrier), then 16
// barrier-free kh-steps: A-frags direct global->reg->bf16 (2-deep static
// prefetch), 8x ds_read_b128 B-frags, 16 MFMA (setprio). launch_bounds(512,2)
// -> 256-VGPR budget (slack so scheduler keeps the pipeline; R6/R7 lesson).
// 4 panels of a row-band co-located on one XCD for L2 reuse of A. Partial
// Wo-dot per panel -> atomicAdd into zeroed scores.
//
// Workspace (1,152 KB):
//   [0, 512K)     : We packed bf16 frag-granules (R6 layout, panel-contiguous)
//   [512K, 640K)  : comb_t f32 [512 col][64 b]  (transposed)
//   [640K, 1152K) : scores f32 [64][2048]  (zeroed by prep_pack)

typedef __attribute__((ext_vector_type(4))) float f32x4;
typedef __attribute__((ext_vector_type(8))) __bf16 bf16x8;
typedef __attribute__((ext_vector_type(8))) unsigned short u16x8;

#define AS3 __attribute__((address_space(3)))
#define AS1 __attribute__((address_space(1)))

__device__ __forceinline__ float fast_tanh(float x) {
  float t = __expf(-2.0f * __builtin_fabsf(x));
  float r = (1.0f - t) * __builtin_amdgcn_rcpf(1.0f + t);
  return __builtin_copysignf(r, x);
}

// ---------------- prep 1: comb_t[o][b] = (mean_l hidden @ Wh^T + bh + be)^T --
__global__ void prep_comb_kernel(const float* __restrict__ hidden,
                                 const float* __restrict__ Wh,
                                 const float* __restrict__ bh,
                                 const float* __restrict__ be,
                                 float* __restrict__ comb_t) {
  __shared__ float hb[512];
  const int b = blockIdx.x, tid = threadIdx.x;  // 512 threads, tid = o
  hb[tid] = 0.5f * (hidden[b * 512 + tid] + hidden[32768 + b * 512 + tid]);
  __syncthreads();
  const f32x4* wr = (const f32x4*)(Wh + tid * 512);
  const f32x4* hv = (const f32x4*)hb;
  float s = 0.f;
  for (int k = 0; k < 128; ++k) {
    f32x4 w = wr[k], x = hv[k];
    s += w.x * x.x + w.y * x.y + w.z * x.z + w.w * x.w;
  }
  comb_t[tid * 64 + b] = s + bh[tid] + be[tid];
}

// ---------------- prep 2: pack We -> bf16 B-fragment granules; zero scores ---
// gid granule: lane = gid&63, nt = (gid>>6)&3, kh = (gid>>8)&15, nh = gid>>12.
// col = nh*64 + nt*16 + (lane&15), k = kh*32 + (lane>>4)*8.
// Panel p (128 cols) = nh {2p, 2p+1} -> contiguous 131072-byte region.
__global__ void prep_pack_kernel(const float* __restrict__ We,
                                 unsigned short* __restrict__ wsw,
                                 float* __restrict__ scores) {
  const int gid = blockIdx.x * 256 + threadIdx.x;  // 0..32767
  const int lane = gid & 63;
  const int nt = (gid >> 6) & 3;
  const int kh = (gid >> 8) & 15;
  const int nh = gid >> 12;
  const int col = nh * 64 + nt * 16 + (lane & 15);
  const int k = kh * 32 + (lane >> 4) * 8;
  const float* src = We + col * 512 + k;
  u16x8 p;
#pragma unroll
  for (int e = 0; e < 8; ++e)
    p[e] = __builtin_bit_cast(unsigned short, (__bf16)src[e]);
  *(u16x8*)(wsw + (long)gid * 8) = p;
  ((f32x4*)scores)[gid] = (f32x4){0.f, 0.f, 0.f, 0.f};  // zero for atomics
}

// ---------------- main: panel-streaming GEMM + tanh + Wo-dot -----------------
// grid 2048: xcd = bid&7, j = bid>>3; band = xcd*64 + (j>>2) (256 rows),
// panel = j&3 (128 cols). 4 panels of a band share the XCD's L2 copy of A.
__global__ __launch_bounds__(512, 2) void gemm_score_kernel(
    const float* __restrict__ enc,            // [131072, 512] (row = t*64+b)
    const unsigned short* __restrict__ wsw,   // packed We frags
    const float* __restrict__ comb_t,         // [512][64]
    const float* __restrict__ Wo,             // [512]
    float* __restrict__ scores)               // [64][2048] (atomic partials)
{
  __shared__ __align__(16) unsigned char Blds[131072];  // [nh2][kh][nt][lane] granules

  const int tid = threadIdx.x;
  const int lane = tid & 63;
  const int wave = tid >> 6;
  const int l15 = lane & 15;
  const int lq = lane >> 4;

  const int bid = blockIdx.x;
  const int xcd = bid & 7;
  const int j = bid >> 3;
  const int band = xcd * 64 + (j >> 2);
  const int panel = j & 3;
  const long r0 = (long)band * 256;

  // ---- stage B panel: 128 KB glds, linear ----
  const unsigned char* bsrc = (const unsigned char*)wsw + (long)panel * 131072 + tid * 16;
#pragma unroll
  for (int r = 0; r < 16; ++r)
    __builtin_amdgcn_global_load_lds((const AS1 unsigned int*)(bsrc + r * 8192),
                                     (AS3 unsigned int*)(&Blds[tid * 16 + r * 8192]),
                                     16, 0, 0);
  __syncthreads();  // only barrier; waves free-run after

  // ---- per-wave: 32 rows x 128 cols, K=512 in 16 steps ----
  // A-frag rows: r0 + wave*32 + m*16 + l15, k = kh*32 + lq*8 (f32x8)
  const float* ag0 = enc + (r0 + wave * 32 + l15) * 512 + lq * 8;
  const float* ag1 = ag0 + 16 * 512;

  f32x4 acc[2][8];
#pragma unroll
  for (int m = 0; m < 2; ++m)
#pragma unroll
    for (int g = 0; g < 8; ++g) acc[m][g] = (f32x4){0.f, 0.f, 0.f, 0.f};

  // 2-deep A prefetch, static indices (full unroll)
  f32x4 ap[2][2][2];  // [depth][m][half]
#pragma unroll
  for (int d = 0; d < 2; ++d) {
    ap[d][0][0] = *(const f32x4*)(ag0 + d * 32);
    ap[d][0][1] = *(const f32x4*)(ag0 + d * 32 + 4);
    ap[d][1][0] = *(const f32x4*)(ag1 + d * 32);
    ap[d][1][1] = *(const f32x4*)(ag1 + d * 32 + 4);
  }

#pragma unroll
  for (int kh = 0; kh < 16; ++kh) {
    // cvt current A regs -> af
    bf16x8 af[2];
#pragma unroll
    for (int m = 0; m < 2; ++m) {
      f32x4 lo = ap[kh & 1][m][0], hi = ap[kh & 1][m][1];
      bf16x8 v;
      v[0] = (__bf16)lo.x; v[1] = (__bf16)lo.y; v[2] = (__bf16)lo.z; v[3] = (__bf16)lo.w;
      v[4] = (__bf16)hi.x; v[5] = (__bf16)hi.y; v[6] = (__bf16)hi.z; v[7] = (__bf16)hi.w;
      af[m] = v;
    }
    // issue A prefetch for kh+2
    if (kh + 2 < 16) {
      ap[kh & 1][0][0] = *(const f32x4*)(ag0 + (kh + 2) * 32);
      ap[kh & 1][0][1] = *(const f32x4*)(ag0 + (kh + 2) * 32 + 4);
      ap[kh & 1][1][0] = *(const f32x4*)(ag1 + (kh + 2) * 32);
      ap[kh & 1][1][1] = *(const f32x4*)(ag1 + (kh + 2) * 32 + 4);
    }

    // B frags from LDS: ntg 0..7 -> byte = (ntg>>2)*65536 + kh*4096 + (ntg&3)*1024 + lane*16
    bf16x8 bf[8];
#pragma unroll
    for (int g = 0; g < 8; ++g)
      bf[g] = *(const bf16x8*)(&Blds[(unsigned)((g >> 2) * 65536 + kh * 4096 + (g & 3) * 1024 + lane * 16)]);

    __builtin_amdgcn_s_setprio(1);
#pragma unroll
    for (int g = 0; g < 8; ++g) {
      acc[0][g] = __builtin_amdgcn_mfma_f32_16x16x32_bf16(af[0], bf[g], acc[0][g], 0, 0, 0);
      acc[1][g] = __builtin_amdgcn_mfma_f32_16x16x32_bf16(af[1], bf[g], acc[1][g], 0, 0, 0);
    }
    __builtin_amdgcn_s_setprio(0);
  }

  // ---- epilogue: partial Wo-dot over this panel's 128 cols ----
  // D frag: row = r0 + wave*32 + m*16 + lq*4 + q; col = panel*128 + g*16 + l15.
  float wo[8];
#pragma unroll
  for (int g = 0; g < 8; ++g) wo[g] = Wo[panel * 128 + g * 16 + l15];

  const int brow = (wave & 1) * 32;  // r0 ≡ 0 mod 64; b = brow + m*16 + lq*4 + q
#pragma unroll
  for (int m = 0; m < 2; ++m) {
#pragma unroll
    for (int q = 0; q < 4; ++q) {
      const int b = brow + m * 16 + lq * 4 + q;
      float s = 0.f;
#pragma unroll
      for (int g = 0; g < 8; ++g) {
        const int col = panel * 128 + g * 16 + l15;
        const float x = acc[m][g][q] + comb_t[col * 64 + b];
        s += fast_tanh(x) * wo[g];
      }
      s += __shfl_xor(s, 1, 16);
      s += __shfl_xor(s, 2, 16);
      s += __shfl_xor(s, 4, 16);
      s += __shfl_xor(s, 8, 16);
      if (l15 == 0) {
        const long row = r0 + wave * 32 + m * 16 + lq * 4 + q;
        atomicAdd(scores + (row & 63) * 2048 + (row >> 6), s);
      }
    }
  }
}

// ---------------- masked softmax over valid prefix ---------------------------
__global__ void softmax_kernel(const float* __restrict__ scores,
                               const int* __restrict__ enc_len,
                               float* __restrict__ out) {
  const int b = blockIdx.x;
  const int tid = threadIdx.x;  // 256
  const int lane = tid & 63;
  const int wv = tid >> 6;
  __shared__ float red[4];
  const int n = enc_len[b];
  const float* sc = scores + (long)b * 2048;

  float v[8];
  float m = -1e30f;
#pragma unroll
  for (int j = 0; j < 8; ++j) {
    const int t = tid + j * 256;
    v[j] = sc[t];
    if (t < n) m = fmaxf(m, v[j]);
  }
#pragma unroll
  for (int k = 32; k; k >>= 1) m = fmaxf(m, __shfl_xor(m, k, 64));
  if (lane == 0) red[wv] = m;
  __syncthreads();
  m = fmaxf(fmaxf(red[0], red[1]), fmaxf(red[2], red[3]));
  __syncthreads();

  float s = 0.f;
#pragma unroll
  for (int j = 0; j < 8; ++j) {
    const int t = tid + j * 256;
    const float e = (t < n) ? __expf(v[j] - m) : 0.f;
    v[j] = e;
    s += e;
  }
#pragma unroll
  for (int k = 32; k; k >>= 1) s += __shfl_xor(s, k, 64);
  if (lane == 0) red[wv] = s;
  __syncthreads();
  s = red[0] + red[1] + red[2] + red[3];
  const float inv = 1.0f / s;
#pragma unroll
  for (int j = 0; j < 8; ++j) {
    const int t = tid + j * 256;
    out[(long)b * 2048 + t] = v[j] * inv;
  }
}

extern "C" void kernel_launch(void* const* d_in, const int* in_sizes, int n_in,
                              void* d_out, int out_size, void* d_ws, size_t ws_size,
                              hipStream_t stream) {
  const float* hidden = (const float*)d_in[0];   // [2,64,512]
  const float* enc    = (const float*)d_in[1];   // [2048,64,512]
  const int*   enclen = (const int*)d_in[2];     // [64]
  const float* Wh     = (const float*)d_in[3];   // [512,512]
  const float* bh     = (const float*)d_in[4];   // [512]
  const float* We     = (const float*)d_in[5];   // [512,512]
  const float* be     = (const float*)d_in[6];   // [512]
  const float* Wo     = (const float*)d_in[7];   // [512]
  // d_in[8] = bo: softmax-invariant, dropped
  float* out = (float*)d_out;

  uint8_t* ws = (uint8_t*)d_ws;
  unsigned short* wsw = (unsigned short*)ws;             // 512 KB packed We
  float* comb_t = (float*)(ws + 524288);                 // 128 KB [512][64]
  float* scores = (float*)(ws + 524288 + 131072);        // 512 KB

  hipLaunchKernelGGL(prep_comb_kernel, dim3(64), dim3(512), 0, stream,
                     hidden, Wh, bh, be, comb_t);
  hipLaunchKernelGGL(prep_pack_kernel, dim3(128), dim3(256), 0, stream,
                     We, wsw, scores);
  hipLaunchKernelGGL(gemm_score_kernel, dim3(2048), dim3(512), 0, stream,
                     enc, wsw, comb_t, Wo, scores);
  hipLaunchKernelGGL(softmax_kernel, dim3(64), dim3(256), 0, stream,
                     scores, enclen, out);
}